// Round 3
// baseline (75.695 us; speedup 1.0000x reference)
//
#include <hip/hip_runtime.h>

// DepthLossV2: sum over lower triangle (i>=j) of piecewise penalty on
// d0 = p[i]-p[j], s = (i-j)*a, a = STEP*z_spacing*nth_slice:
//   d0 < 0           -> -d0
//   0 <= d0 < 0.2s   -> 0.2s - d0
//   else             -> max(d0 - s, 0)
// With n0 = pj - pi and dij = i-j (float, exact, < 2^24):
//   e1 = fma(dij, 0.2a, n0)   (= 0.2s - d0)
//   t  = fma(dij, a,   n0)    (= s - d0)
//   c  = (n0 > 0) ? n0 : max3(e1, -t, 0)
//
// Round-3 structure:
//  * 544 blocks, ONE 512x128 tile each (2 rows/thread -> each ds_read_b128
//    of 4 j-values feeds 8 element-evals; halves LDS traffic + overhead).
//  * single fused dispatch: per-block double partial atomicAdd'd into a
//    16-B header (zeroed by hipMemsetAsync each launch -> poison-safe);
//    last-arriving block (counter) writes out. No finalize kernel.
//  * NO cooperative grid.sync (round 1: ~100us stall on MI355X).
// loss = sum / (n*n)

typedef float f32x2 __attribute__((ext_vector_type(2)));

constexpr int TPB  = 256;   // threads per block
constexpr int TR   = 512;   // tile rows (2 per thread)
constexpr int COLS = 128;   // tile cols

struct WsHeader { double acc; unsigned int cnt; unsigned int pad; };

__global__ __launch_bounds__(TPB, 3) void depth_loss_fused(
    const float* __restrict__ p,
    const float* __restrict__ zsp,
    const float* __restrict__ nsl,
    WsHeader* __restrict__ hdr,
    float* __restrict__ out,
    int n, int nblocks)
{
    // block b -> (ri, cj): row-tile ri has 4*(ri+1) col-tiles, prefix 2*ri*(ri+1)
    int b = blockIdx.x;
    int ri = (int)((sqrtf(2.0f * (float)b + 1.0f) - 1.0f) * 0.5f);
    while (2 * (ri + 1) * (ri + 2) <= b) ++ri;
    while (2 * ri * (ri + 1) > b) --ri;
    int cj = b - 2 * ri * (ri + 1);

    int tid = threadIdx.x;
    int i0 = ri * TR + tid;          // row 0 of this thread
    int i1 = i0 + TPB;               // row 1 (i0 + 256)
    float pi0 = p[i0];
    float pi1 = p[i1];
    f32x2 pi2_0 = { pi0, pi0 };
    f32x2 pi2_1 = { pi1, pi1 };

    __shared__ __align__(16) float pjs[COLS];
    int jbase = cj * COLS;
    if (tid < COLS / 4)
        ((float4*)pjs)[tid] = ((const float4*)(p + jbase))[tid];
    __syncthreads();

    float a   = zsp[0] * nsl[0];     // STEP == 1.0, a > 0
    float a02 = 0.2f * a;
    f32x2 av   = { a,   a   };
    f32x2 a02v = { a02, a02 };
    f32x2 four = { 4.0f, 4.0f };
    f32x2 zero = { 0.0f, 0.0f };

    float dij0 = (float)(i0 - jbase);            // exact in float
    f32x2 d2a0 = { dij0,          dij0 - 1.0f }; // row0, j-slots (x,y)
    f32x2 d2b0 = { dij0 - 2.0f,   dij0 - 3.0f }; // row0, j-slots (z,w)
    f32x2 d2a1 = { dij0 + 256.0f, dij0 + 255.0f }; // row1
    f32x2 d2b1 = { dij0 + 254.0f, dij0 + 253.0f };

    f32x2 acc2a0 = zero, acc2b0 = zero, acc2a1 = zero, acc2b1 = zero;
    const float4* pj4 = (const float4*)pjs;

#define GROUP_BODY(VA, PI2, D2, ACC, MASKED)                          \
    {                                                                 \
        f32x2 n0 = (VA) - PI2;                      /* v_pk_add  */   \
        f32x2 e1 = __builtin_elementwise_fma(D2, a02v, n0);           \
        f32x2 t  = __builtin_elementwise_fma(D2, av,   n0);           \
        f32x2 cp = __builtin_elementwise_max(                         \
                       __builtin_elementwise_max(e1, -t), zero);      \
        f32x2 c;                                                      \
        c.x = (n0.x > 0.0f) ? n0.x : cp.x;                            \
        c.y = (n0.y > 0.0f) ? n0.y : cp.y;                            \
        if (MASKED) {                                                 \
            c.x = (D2.x >= 0.0f) ? c.x : 0.0f;                        \
            c.y = (D2.y >= 0.0f) ? c.y : 0.0f;                        \
        }                                                             \
        ACC += c;                                    /* v_pk_add */   \
        D2  -= four;                                 /* v_pk_add */   \
    }

    if (cj < 4 * ri) {
        // fully interior: every j in tile < every i in tile (both rows)
        #pragma unroll 4
        for (int q = 0; q < COLS / 4; ++q) {
            float4 v = pj4[q];
            f32x2 va = { v.x, v.y };
            f32x2 vb = { v.z, v.w };
            GROUP_BODY(va, pi2_0, d2a0, acc2a0, false)
            GROUP_BODY(vb, pi2_0, d2b0, acc2b0, false)
            GROUP_BODY(va, pi2_1, d2a1, acc2a1, false)
            GROUP_BODY(vb, pi2_1, d2b1, acc2b1, false)
        }
    } else {
        // diagonal-touching tile: mask j > i per component via sign of dij
        #pragma unroll 4
        for (int q = 0; q < COLS / 4; ++q) {
            float4 v = pj4[q];
            f32x2 va = { v.x, v.y };
            f32x2 vb = { v.z, v.w };
            GROUP_BODY(va, pi2_0, d2a0, acc2a0, true)
            GROUP_BODY(vb, pi2_0, d2b0, acc2b0, true)
            GROUP_BODY(va, pi2_1, d2a1, acc2a1, true)
            GROUP_BODY(vb, pi2_1, d2b1, acc2b1, true)
        }
    }
#undef GROUP_BODY

    f32x2 acc2 = (acc2a0 + acc2b0) + (acc2a1 + acc2b1);
    float acc = acc2.x + acc2.y;

    // wave-64 shuffle reduction
    for (int off = 32; off > 0; off >>= 1)
        acc += __shfl_down(acc, off, 64);

    __shared__ float wsum[TPB / 64];
    if ((tid & 63) == 0) wsum[tid >> 6] = acc;
    __syncthreads();

    if (tid == 0) {
        double bs = (double)((wsum[0] + wsum[1]) + (wsum[2] + wsum[3]));
        atomicAdd(&hdr->acc, bs);                 // device-scope, cross-XCD
        __threadfence();                          // release before counter
        unsigned int old = atomicAdd(&hdr->cnt, 1u);
        if (old == (unsigned int)(nblocks - 1)) {
            __threadfence();
            double tot = atomicAdd(&hdr->acc, 0.0);  // coherent RMW read
            double inv_nn = 1.0 / ((double)n * (double)n);
            out[0] = (float)(tot * inv_nn);
        }
    }
}

extern "C" void kernel_launch(void* const* d_in, const int* in_sizes, int n_in,
                              void* d_out, int out_size, void* d_ws, size_t ws_size,
                              hipStream_t stream) {
    const float* p   = (const float*)d_in[0];
    const float* zsp = (const float*)d_in[1];
    const float* nsl = (const float*)d_in[2];
    float* out = (float*)d_out;
    WsHeader* hdr = (WsHeader*)d_ws;

    int n = in_sizes[0];                  // 8192, divisible by TR
    int nrt = n / TR;                     // 16
    int nblocks = 2 * nrt * (nrt + 1);    // 544

    hipMemsetAsync(d_ws, 0, sizeof(WsHeader), stream);   // zero acc + cnt
    depth_loss_fused<<<nblocks, TPB, 0, stream>>>(p, zsp, nsl, hdr, out, n, nblocks);
}

// Round 4
// 67.582 us; speedup vs baseline: 1.1200x; 1.1200x over previous
//
#include <hip/hip_runtime.h>

// DepthLossV2: sum over lower triangle (i>=j) of piecewise penalty on
// d0 = p[i]-p[j], s = (i-j)*a, a = STEP*z_spacing*nth_slice:
//   d0 < 0           -> -d0
//   0 <= d0 < 0.2s   -> 0.2s - d0
//   else             -> max(d0 - s, 0)
// With n0 = pj - pi and dij = i-j (float, exact):
//   e1 = fma(dij, 0.2a, n0)   (= 0.2s - d0)
//   t  = fma(dij, a,   n0)    (= s - d0)
//   c  = (n0 > 0) ? n0 : max3(e1, -t, 0)
//
// MEASURED-BEST structure (round 2, 67.7us; round 0 variant 67.6us):
// 1024 blocks grid-stride over 1056 tiles of 256x128; per-thread register
// accumulation across tiles; ONE block reduction at the end; double partial
// per block; tiny finalize kernel.
// Rejected by measurement:
//  * cooperative grid.sync       -> +113us (round 1: VALUBusy 4.9%, barrier stall)
//  * hipMemsetAsync + atomic tail -> +8us  (round 3: blit-memset dispatch cost)
// The timed window is dominated by the harness's 256MiB poison fill
// (39.5us @ 85% HBM peak) + fixed reset dispatches; our controllable slice
// is ~8-10us and two plain dependent dispatches is its measured minimum.
// loss = sum / (n*n)

typedef float f32x2 __attribute__((ext_vector_type(2)));

constexpr int ROWS = 256;   // threads per block, one i-row each
constexpr int COLS = 128;   // j-extent per tile
constexpr int GRID = 1024;  // 4 blocks/CU co-resident (launch_bounds(256,4))

__device__ __forceinline__ float block_tiles_sum(
    const float* __restrict__ p, float a, int ntiles, int tid, float* pjs)
{
    float a02 = 0.2f * a;
    f32x2 av   = { a,   a   };
    f32x2 a02v = { a02, a02 };
    f32x2 four = { 4.0f, 4.0f };
    f32x2 zero = { 0.0f, 0.0f };

    f32x2 acc2a = zero, acc2b = zero;

    for (int b = blockIdx.x; b < ntiles; b += GRID) {
        // tile b -> (ri, cj): row-tile ri has 2*ri+2 col-tiles, prefix = ri*(ri+1)
        int ri = (int)((sqrtf(4.0f * (float)b + 1.0f) - 1.0f) * 0.5f);
        while ((ri + 1) * (ri + 2) <= b) ++ri;
        while (ri * (ri + 1) > b) --ri;
        int cj = b - ri * (ri + 1);

        int i = ri * ROWS + tid;
        float pi = p[i];
        f32x2 pi2 = { pi, pi };

        int jbase = cj * COLS;
        if (tid < COLS / 4)
            ((float4*)pjs)[tid] = ((const float4*)(p + jbase))[tid];
        __syncthreads();

        float dij0 = (float)(i - jbase);          // exact in float (< 2^24)
        f32x2 d2a = { dij0,        dij0 - 1.0f }; // pairs (x,y)
        f32x2 d2b = { dij0 - 2.0f, dij0 - 3.0f }; // pairs (z,w)

        const float4* pj4 = (const float4*)pjs;

#define GROUP_BODY(VA, D2, ACC, MASKED)                               \
        {                                                             \
            f32x2 n0 = (VA) - pi2;                      /* v_pk_add */\
            f32x2 e1 = __builtin_elementwise_fma(D2, a02v, n0);       \
            f32x2 t  = __builtin_elementwise_fma(D2, av,   n0);       \
            f32x2 cp = __builtin_elementwise_max(                     \
                           __builtin_elementwise_max(e1, -t), zero);  \
            f32x2 c;                                                  \
            c.x = (n0.x > 0.0f) ? n0.x : cp.x;                        \
            c.y = (n0.y > 0.0f) ? n0.y : cp.y;                        \
            if (MASKED) {                                             \
                c.x = (D2.x >= 0.0f) ? c.x : 0.0f;                    \
                c.y = (D2.y >= 0.0f) ? c.y : 0.0f;                    \
            }                                                         \
            ACC += c;                                   /* v_pk_add */\
            D2  -= four;                                /* v_pk_add */\
        }

        if (cj < 2 * ri) {
            // fully interior: every j in tile < every i in tile
            #pragma unroll 8
            for (int q = 0; q < COLS / 4; ++q) {
                float4 v = pj4[q];
                f32x2 va = { v.x, v.y };
                f32x2 vb = { v.z, v.w };
                GROUP_BODY(va, d2a, acc2a, false)
                GROUP_BODY(vb, d2b, acc2b, false)
            }
        } else {
            // diagonal-touching tile: mask j > i via sign of dij
            #pragma unroll 8
            for (int q = 0; q < COLS / 4; ++q) {
                float4 v = pj4[q];
                f32x2 va = { v.x, v.y };
                f32x2 vb = { v.z, v.w };
                GROUP_BODY(va, d2a, acc2a, true)
                GROUP_BODY(vb, d2b, acc2b, true)
            }
        }
#undef GROUP_BODY
        __syncthreads();   // pjs reused next tile
    }

    float acc = (acc2a.x + acc2a.y) + (acc2b.x + acc2b.y);

    // wave-64 shuffle reduction, once per block (not per tile)
    for (int off = 32; off > 0; off >>= 1)
        acc += __shfl_down(acc, off, 64);

    __shared__ float wsum[ROWS / 64];
    if ((tid & 63) == 0) wsum[tid >> 6] = acc;
    __syncthreads();

    float bs = 0.0f;
    if (tid == 0)
        bs = (wsum[0] + wsum[1]) + (wsum[2] + wsum[3]);
    return bs;   // valid on tid==0 only
}

__global__ __launch_bounds__(ROWS, 4) void depth_loss_main(
    const float* __restrict__ p,
    const float* __restrict__ zsp,
    const float* __restrict__ nsl,
    double* __restrict__ partials,
    int n)
{
    __shared__ __align__(16) float pjs[COLS];
    int tid = threadIdx.x;
    int nrt = n / ROWS;
    int ntiles = nrt * (nrt + 1);
    float a = zsp[0] * nsl[0];   // STEP == 1.0, a > 0

    float bs = block_tiles_sum(p, a, ntiles, tid, pjs);
    if (tid == 0) partials[blockIdx.x] = (double)bs;
}

__global__ __launch_bounds__(256) void finalize_kernel(
    const double* __restrict__ partials, int nblocks, float* __restrict__ out,
    double inv_nn)
{
    int tid = threadIdx.x;
    double acc = 0.0;
    for (int b = tid; b < nblocks; b += 256) acc += partials[b];
    for (int off = 32; off > 0; off >>= 1)
        acc += __shfl_down(acc, off, 64);
    __shared__ double wsum[4];
    if ((tid & 63) == 0) wsum[tid >> 6] = acc;
    __syncthreads();
    if (tid == 0)
        out[0] = (float)(((wsum[0] + wsum[1]) + (wsum[2] + wsum[3])) * inv_nn);
}

extern "C" void kernel_launch(void* const* d_in, const int* in_sizes, int n_in,
                              void* d_out, int out_size, void* d_ws, size_t ws_size,
                              hipStream_t stream) {
    const float* p   = (const float*)d_in[0];
    const float* zsp = (const float*)d_in[1];
    const float* nsl = (const float*)d_in[2];
    float* out = (float*)d_out;
    double* partials = (double*)d_ws;

    int n = in_sizes[0];              // 8192, divisible by ROWS
    double inv_nn = 1.0 / ((double)n * (double)n);

    depth_loss_main<<<GRID, ROWS, 0, stream>>>(p, zsp, nsl, partials, n);
    finalize_kernel<<<1, 256, 0, stream>>>(partials, GRID, out, inv_nn);
}